// Round 3
// baseline (2278.452 us; speedup 1.0000x reference)
//
#include <hip/hip_runtime.h>
#include <cstddef>

#define BN_EPS 1e-5f

// ---------------------------------------------------------------------------
// Sparse conv for COUT in {64,128}. Block = 256 = 4 waves; each wave handles
// R consecutive output rows (lane = co, CPL = COUT/64 channels per lane).
// Map entries prefetched lane-parallel then broadcast (shfl+readfirstlane) ->
// wave-uniform scalar branches. Inner loop tiles ci by TI=8 and batches ALL
// loads of a tile (W + every row's x) before the FMA block for deep MLP.
// Fused BN pass-1: per-block channel sum/sumsq -> atomicAdd into sums[2*COUT].
// x may be a concat of xA (CINA ch) and xB (CIN-CINA ch).
// ---------------------------------------------------------------------------
template<int CIN, int CINA, int COUT, int R>
__global__ __launch_bounds__(256)
void sconv_big(const float* __restrict__ xA, const float* __restrict__ xB,
               const float* __restrict__ W, const int* __restrict__ map,
               int Nout, float* __restrict__ out, float* __restrict__ sums)
{
    constexpr int CINB = CIN - CINA;
    constexpr int CPL  = COUT / 64;
    constexpr int TI   = 8;
    const int lane = threadIdx.x & 63;
    const int wave = threadIdx.x >> 6;
    const int row0 = (blockIdx.x * 4 + wave) * R;

    // Prefetch all 27 map entries for each of this wave's R rows.
    int mk[R];
    #pragma unroll
    for (int r = 0; r < R; ++r) {
        const int j = row0 + r;
        mk[r] = (lane < 27 && j < Nout) ? map[(size_t)lane * Nout + j] : -1;
    }

    float acc[R][CPL];
    #pragma unroll
    for (int r = 0; r < R; ++r)
        #pragma unroll
        for (int c = 0; c < CPL; ++c) acc[r][c] = 0.f;

    for (int k = 0; k < 27; ++k) {
        int m[R];
        bool any = false;
        #pragma unroll
        for (int r = 0; r < R; ++r) {
            m[r] = __builtin_amdgcn_readfirstlane(__shfl(mk[r], k));
            any |= (m[r] >= 0);
        }
        if (!any) continue;

        const float* Wk = W + (size_t)k * CIN * COUT + lane;

        #pragma unroll
        for (int ci = 0; ci < CIN; ci += TI) {
            // ---- batched W tile loads (coalesced, 256B each) ----
            float w[TI][CPL];
            #pragma unroll
            for (int u = 0; u < TI; ++u)
                #pragma unroll
                for (int c = 0; c < CPL; ++c)
                    w[u][c] = Wk[(size_t)(ci + u) * COUT + c * 64];

            // ---- batched x tile loads (wave-uniform broadcast, 2x16B/row) --
            float4 xv0[R], xv1[R];
            #pragma unroll
            for (int r = 0; r < R; ++r) {
                if (m[r] < 0) continue;  // wave-uniform scalar branch
                const float* xr = (ci < CINA)
                    ? (xA + (size_t)m[r] * CINA + ci)
                    : (xB + (size_t)m[r] * CINB + (ci - CINA));
                xv0[r] = *(const float4*)xr;
                xv1[r] = *(const float4*)(xr + 4);
            }

            // ---- FMA block ----
            #pragma unroll
            for (int r = 0; r < R; ++r) {
                if (m[r] < 0) continue;
                const float xx[TI] = {xv0[r].x, xv0[r].y, xv0[r].z, xv0[r].w,
                                      xv1[r].x, xv1[r].y, xv1[r].z, xv1[r].w};
                #pragma unroll
                for (int u = 0; u < TI; ++u)
                    #pragma unroll
                    for (int c = 0; c < CPL; ++c)
                        acc[r][c] = fmaf(xx[u], w[u][c], acc[r][c]);
            }
        }
    }

    // ---- write out + per-wave BN partial sums ----
    float s[CPL], s2[CPL];
    #pragma unroll
    for (int c = 0; c < CPL; ++c) { s[c] = 0.f; s2[c] = 0.f; }
    #pragma unroll
    for (int r = 0; r < R; ++r) {
        const int j = row0 + r;
        if (j < Nout) {
            #pragma unroll
            for (int c = 0; c < CPL; ++c) {
                const float v = acc[r][c];
                out[(size_t)j * COUT + c * 64 + lane] = v;
                s[c] += v;
                s2[c] += v * v;
            }
        }
    }

    // ---- block-level reduce of BN partials, one atomicAdd per channel ----
    __shared__ float red[4][2 * CPL][64];
    #pragma unroll
    for (int c = 0; c < CPL; ++c) {
        red[wave][c][lane] = s[c];
        red[wave][CPL + c][lane] = s2[c];
    }
    __syncthreads();
    if (wave == 0) {
        #pragma unroll
        for (int c = 0; c < CPL; ++c) {
            float S = 0.f, S2 = 0.f;
            #pragma unroll
            for (int w2 = 0; w2 < 4; ++w2) {
                S  += red[w2][c][lane];
                S2 += red[w2][CPL + c][lane];
            }
            atomicAdd(&sums[c * 64 + lane], S);
            atomicAdd(&sums[COUT + c * 64 + lane], S2);
        }
    }
}

// ---------------------------------------------------------------------------
// conv0: CIN=16, COUT=32. One row per half-wave; block 256 = 8 rows.
// Fused BN pass-1 via LDS block reduce.
// ---------------------------------------------------------------------------
__global__ __launch_bounds__(256)
void sconv0(const float* __restrict__ x, const float* __restrict__ W,
            const int* __restrict__ map, int N, float* __restrict__ out,
            float* __restrict__ sums)
{
    const int tid  = threadIdx.x;
    const int lane = tid & 63;
    const int l32  = tid & 31;
    const int co   = l32;
    const int j    = blockIdx.x * 8 + (tid >> 5);

    int mk = (l32 < 27 && j < N) ? map[(size_t)l32 * N + j] : -1;

    float a0 = 0.f, a1 = 0.f, a2 = 0.f, a3 = 0.f;
    for (int k = 0; k < 27; ++k) {
        const int m = __shfl(mk, (lane & 32) + k);
        if (m < 0) continue;
        const float* xr = x + (size_t)m * 16;
        const float* wk = W + (size_t)k * 16 * 32 + co;
        const float4 xv0 = *(const float4*)xr;
        const float4 xv1 = *(const float4*)(xr + 4);
        const float4 xv2 = *(const float4*)(xr + 8);
        const float4 xv3 = *(const float4*)(xr + 12);
        a0 = fmaf(xv0.x, wk[0 * 32],  a0); a1 = fmaf(xv0.y, wk[1 * 32],  a1);
        a2 = fmaf(xv0.z, wk[2 * 32],  a2); a3 = fmaf(xv0.w, wk[3 * 32],  a3);
        a0 = fmaf(xv1.x, wk[4 * 32],  a0); a1 = fmaf(xv1.y, wk[5 * 32],  a1);
        a2 = fmaf(xv1.z, wk[6 * 32],  a2); a3 = fmaf(xv1.w, wk[7 * 32],  a3);
        a0 = fmaf(xv2.x, wk[8 * 32],  a0); a1 = fmaf(xv2.y, wk[9 * 32],  a1);
        a2 = fmaf(xv2.z, wk[10 * 32], a2); a3 = fmaf(xv2.w, wk[11 * 32], a3);
        a0 = fmaf(xv3.x, wk[12 * 32], a0); a1 = fmaf(xv3.y, wk[13 * 32], a1);
        a2 = fmaf(xv3.z, wk[14 * 32], a2); a3 = fmaf(xv3.w, wk[15 * 32], a3);
    }
    const float v = (j < N) ? ((a0 + a1) + (a2 + a3)) : 0.f;
    if (j < N) out[(size_t)j * 32 + co] = v;

    __shared__ float red[2][256];
    red[0][tid] = v;
    red[1][tid] = v * v;
    __syncthreads();
    if (tid < 32) {
        float S = 0.f, S2 = 0.f;
        #pragma unroll
        for (int g = 0; g < 8; ++g) {
            S  += red[0][tid + 32 * g];
            S2 += red[1][tid + 32 * g];
        }
        atomicAdd(&sums[tid], S);
        atomicAdd(&sums[32 + tid], S2);
    }
}

// ---------------------------------------------------------------------------
// conv0t: x = concat(d1[*,64], s1[*,32]), COUT=2. 32 lanes cooperate per row.
// ---------------------------------------------------------------------------
__global__ __launch_bounds__(256)
void sconv0t(const float* __restrict__ d1, const float* __restrict__ s1,
             const float* __restrict__ W /*[27,96,2]*/,
             const int* __restrict__ map, int N, float* __restrict__ out)
{
    const int tid  = threadIdx.x;
    const int lane = tid & 63;
    const int l32  = tid & 31;
    const int j    = blockIdx.x * 8 + (tid >> 5);

    int mk = (l32 < 27 && j < N) ? map[(size_t)l32 * N + j] : -1;

    float a0 = 0.f, a1 = 0.f;
    for (int k = 0; k < 27; ++k) {
        const int m = __shfl(mk, (lane & 32) + k);
        if (m < 0) continue;
        const float* w = W + (size_t)k * 96 * 2;
        const float x0 = d1[(size_t)m * 64 + l32];
        const float x1 = d1[(size_t)m * 64 + l32 + 32];
        const float x2 = s1[(size_t)m * 32 + l32];
        a0 = fmaf(x0, w[l32 * 2 + 0], a0);
        a1 = fmaf(x0, w[l32 * 2 + 1], a1);
        a0 = fmaf(x1, w[(l32 + 32) * 2 + 0], a0);
        a1 = fmaf(x1, w[(l32 + 32) * 2 + 1], a1);
        a0 = fmaf(x2, w[(l32 + 64) * 2 + 0], a0);
        a1 = fmaf(x2, w[(l32 + 64) * 2 + 1], a1);
    }
    #pragma unroll
    for (int off = 1; off < 32; off <<= 1) {
        a0 += __shfl_xor(a0, off, 32);
        a1 += __shfl_xor(a1, off, 32);
    }
    if (l32 == 0 && j < N) {
        out[(size_t)j * 2 + 0] = a0;
        out[(size_t)j * 2 + 1] = a1;
    }
}

// ---------------------------------------------------------------------------
// BN pass 2: x = relu((x - mu) * rsqrt(var + eps) * g + b), in place
// ---------------------------------------------------------------------------
template<int C>
__global__ __launch_bounds__(256)
void bn_apply_kernel(float* __restrict__ x, int N,
                     const float* __restrict__ sums,
                     const float* __restrict__ g, const float* __restrict__ b)
{
    const int tid = blockIdx.x * blockDim.x + threadIdx.x;
    const int c = tid % C;
    const float invN = 1.0f / (float)N;
    const float mean = sums[c] * invN;
    float var = sums[C + c] * invN - mean * mean;
    var = fmaxf(var, 0.f);
    const float sc = g[c] * rsqrtf(var + BN_EPS);
    const float sh = b[c] - mean * sc;
    const int rows_stride = (gridDim.x * blockDim.x) / C;
    for (int j = tid / C; j < N; j += rows_stride) {
        const size_t i = (size_t)j * C + c;
        const float v = fmaf(x[i], sc, sh);
        x[i] = v > 0.f ? v : 0.f;
    }
}

// ---------------------------------------------------------------------------
extern "C" void kernel_launch(void* const* d_in, const int* in_sizes, int n_in,
                              void* d_out, int out_size, void* d_ws, size_t ws_size,
                              hipStream_t stream)
{
    const float* feats = (const float*)d_in[0];
    const float* W0  = (const float*)d_in[1];
    const float* g0  = (const float*)d_in[2];
    const float* b0  = (const float*)d_in[3];
    const float* W1  = (const float*)d_in[4];
    const float* g1  = (const float*)d_in[5];
    const float* b1  = (const float*)d_in[6];
    const float* W2  = (const float*)d_in[7];
    const float* g2  = (const float*)d_in[8];
    const float* b2  = (const float*)d_in[9];
    const float* W2t = (const float*)d_in[10];
    const float* g2t = (const float*)d_in[11];
    const float* b2t = (const float*)d_in[12];
    const float* W1t = (const float*)d_in[13];
    const float* g1t = (const float*)d_in[14];
    const float* b1t = (const float*)d_in[15];
    const float* W0t = (const float*)d_in[16];
    const int* map0  = (const int*)d_in[17];
    const int* map1  = (const int*)d_in[18];
    const int* map2  = (const int*)d_in[19];
    const int* map2t = (const int*)d_in[20];
    const int* map1t = (const int*)d_in[21];
    const int* map0t = (const int*)d_in[22];

    const int N0 = in_sizes[0] / 16;
    const int N1 = in_sizes[18] / 27;
    const int N2 = in_sizes[19] / 27;

    float* ws = (float*)d_ws;
    float* y0 = ws;                      // [N0,32]  s1
    float* y1 = y0 + (size_t)N0 * 32;    // [N1,64]  s2
    float* y2 = y1 + (size_t)N1 * 64;    // [N2,128] s4
    float* y3 = y2 + (size_t)N2 * 128;   // [N1,64]  d2
    float* y4 = y3 + (size_t)N1 * 64;    // [N0,64]  d1
    float* sums  = y4 + (size_t)N0 * 64; // BN accumulators (704 floats)
    float* sums0 = sums;        // 2*32
    float* sums1 = sums + 64;   // 2*64
    float* sums2 = sums + 192;  // 2*128
    float* sums3 = sums + 448;  // 2*64
    float* sums4 = sums + 576;  // 2*64

    hipMemsetAsync(sums, 0, 704 * sizeof(float), stream);

    // block0: feats[N0,16] -> y0[N0,32]
    sconv0<<<(N0 + 7) / 8, 256, 0, stream>>>(feats, W0, map0, N0, y0, sums0);
    bn_apply_kernel<32><<<512, 256, 0, stream>>>(y0, N0, sums0, g0, b0);

    // block1: s1[N0,32] -> y1[N1,64]   (R=8 -> 32 rows/block)
    sconv_big<32, 32, 64, 8><<<(N1 + 31) / 32, 256, 0, stream>>>(
        y0, nullptr, W1, map1, N1, y1, sums1);
    bn_apply_kernel<64><<<512, 256, 0, stream>>>(y1, N1, sums1, g1, b1);

    // block2: s2[N1,64] -> y2[N2,128]  (R=4 -> 16 rows/block)
    sconv_big<64, 64, 128, 4><<<(N2 + 15) / 16, 256, 0, stream>>>(
        y1, nullptr, W2, map2, N2, y2, sums2);
    bn_apply_kernel<128><<<512, 256, 0, stream>>>(y2, N2, sums2, g2, b2);

    // block2_tr: s4[N2,128] -> y3[N1,64]  (R=8 -> 32 rows/block)
    sconv_big<128, 128, 64, 8><<<(N1 + 31) / 32, 256, 0, stream>>>(
        y2, nullptr, W2t, map2t, N1, y3, sums3);
    bn_apply_kernel<64><<<512, 256, 0, stream>>>(y3, N1, sums3, g2t, b2t);

    // block1_tr: concat(d2,s2)[N1,128] -> y4[N0,64]  (R=8)
    sconv_big<128, 64, 64, 8><<<(N0 + 31) / 32, 256, 0, stream>>>(
        y3, y1, W1t, map1t, N0, y4, sums4);
    bn_apply_kernel<64><<<512, 256, 0, stream>>>(y4, N0, sums4, g1t, b1t);

    // block0_tr: concat(d1,s1)[N0,96] -> out[N0,2]
    sconv0t<<<(N0 + 7) / 8, 256, 0, stream>>>(y4, y0, W0t, map0t, N0,
                                              (float*)d_out);
}

// Round 4
// 1904.887 us; speedup vs baseline: 1.1961x; 1.1961x over previous
//
#include <hip/hip_runtime.h>
#include <cstddef>

#define BN_EPS 1e-5f

// ---------------------------------------------------------------------------
// Sparse conv for COUT in {64,128}. Block = 256 = 4 waves; each wave handles
// R consecutive output rows (lane = co, CPL = COUT/64 channels per lane).
// Map entries prefetched lane-parallel then broadcast (shfl+readfirstlane) ->
// wave-uniform scalar branches. Inner loop tiles ci by TI=8 and batches ALL
// loads of a tile (W + every row's x) before the FMA block for deep MLP.
// NOTE: no fused BN here — 25k-block atomicAdd fan-in to 64 addresses cost
// ~600 us in round 3 (VALUBusy 3.4%). Separate bn_reduce is ~free (L3-hot).
// ---------------------------------------------------------------------------
template<int CIN, int CINA, int COUT, int R>
__global__ __launch_bounds__(256)
void sconv_big(const float* __restrict__ xA, const float* __restrict__ xB,
               const float* __restrict__ W, const int* __restrict__ map,
               int Nout, float* __restrict__ out)
{
    constexpr int CINB = CIN - CINA;
    constexpr int CPL  = COUT / 64;
    constexpr int TI   = 8;
    const int lane = threadIdx.x & 63;
    const int wave = threadIdx.x >> 6;
    const int row0 = (blockIdx.x * 4 + wave) * R;

    int mk[R];
    #pragma unroll
    for (int r = 0; r < R; ++r) {
        const int j = row0 + r;
        mk[r] = (lane < 27 && j < Nout) ? map[(size_t)lane * Nout + j] : -1;
    }

    float acc[R][CPL];
    #pragma unroll
    for (int r = 0; r < R; ++r)
        #pragma unroll
        for (int c = 0; c < CPL; ++c) acc[r][c] = 0.f;

    for (int k = 0; k < 27; ++k) {
        int m[R];
        bool any = false;
        #pragma unroll
        for (int r = 0; r < R; ++r) {
            m[r] = __builtin_amdgcn_readfirstlane(__shfl(mk[r], k));
            any |= (m[r] >= 0);
        }
        if (!any) continue;

        const float* Wk = W + (size_t)k * CIN * COUT + lane;

        #pragma unroll
        for (int ci = 0; ci < CIN; ci += TI) {
            float w[TI][CPL];
            #pragma unroll
            for (int u = 0; u < TI; ++u)
                #pragma unroll
                for (int c = 0; c < CPL; ++c)
                    w[u][c] = Wk[(size_t)(ci + u) * COUT + c * 64];

            float4 xv0[R], xv1[R];
            #pragma unroll
            for (int r = 0; r < R; ++r) {
                if (m[r] < 0) continue;  // wave-uniform scalar branch
                const float* xr = (ci < CINA)
                    ? (xA + (size_t)m[r] * CINA + ci)
                    : (xB + (size_t)m[r] * CINB + (ci - CINA));
                xv0[r] = *(const float4*)xr;
                xv1[r] = *(const float4*)(xr + 4);
            }

            #pragma unroll
            for (int r = 0; r < R; ++r) {
                if (m[r] < 0) continue;
                const float xx[TI] = {xv0[r].x, xv0[r].y, xv0[r].z, xv0[r].w,
                                      xv1[r].x, xv1[r].y, xv1[r].z, xv1[r].w};
                #pragma unroll
                for (int u = 0; u < TI; ++u)
                    #pragma unroll
                    for (int c = 0; c < CPL; ++c)
                        acc[r][c] = fmaf(xx[u], w[u][c], acc[r][c]);
            }
        }
    }

    #pragma unroll
    for (int r = 0; r < R; ++r) {
        const int j = row0 + r;
        if (j < Nout) {
            #pragma unroll
            for (int c = 0; c < CPL; ++c)
                out[(size_t)j * COUT + c * 64 + lane] = acc[r][c];
        }
    }
}

// ---------------------------------------------------------------------------
// conv0: CIN=16, COUT=32. One row per half-wave; block 256 = 8 rows.
// ---------------------------------------------------------------------------
__global__ __launch_bounds__(256)
void sconv0(const float* __restrict__ x, const float* __restrict__ W,
            const int* __restrict__ map, int N, float* __restrict__ out)
{
    const int tid  = threadIdx.x;
    const int lane = tid & 63;
    const int l32  = tid & 31;
    const int co   = l32;
    const int j    = blockIdx.x * 8 + (tid >> 5);

    int mk = (l32 < 27 && j < N) ? map[(size_t)l32 * N + j] : -1;

    float a0 = 0.f, a1 = 0.f, a2 = 0.f, a3 = 0.f;
    for (int k = 0; k < 27; ++k) {
        const int m = __shfl(mk, (lane & 32) + k);
        if (m < 0) continue;
        const float* xr = x + (size_t)m * 16;
        const float* wk = W + (size_t)k * 16 * 32 + co;
        const float4 xv0 = *(const float4*)xr;
        const float4 xv1 = *(const float4*)(xr + 4);
        const float4 xv2 = *(const float4*)(xr + 8);
        const float4 xv3 = *(const float4*)(xr + 12);
        a0 = fmaf(xv0.x, wk[0 * 32],  a0); a1 = fmaf(xv0.y, wk[1 * 32],  a1);
        a2 = fmaf(xv0.z, wk[2 * 32],  a2); a3 = fmaf(xv0.w, wk[3 * 32],  a3);
        a0 = fmaf(xv1.x, wk[4 * 32],  a0); a1 = fmaf(xv1.y, wk[5 * 32],  a1);
        a2 = fmaf(xv1.z, wk[6 * 32],  a2); a3 = fmaf(xv1.w, wk[7 * 32],  a3);
        a0 = fmaf(xv2.x, wk[8 * 32],  a0); a1 = fmaf(xv2.y, wk[9 * 32],  a1);
        a2 = fmaf(xv2.z, wk[10 * 32], a2); a3 = fmaf(xv2.w, wk[11 * 32], a3);
        a0 = fmaf(xv3.x, wk[12 * 32], a0); a1 = fmaf(xv3.y, wk[13 * 32], a1);
        a2 = fmaf(xv3.z, wk[14 * 32], a2); a3 = fmaf(xv3.w, wk[15 * 32], a3);
    }
    if (j < N) out[(size_t)j * 32 + co] = (a0 + a1) + (a2 + a3);
}

// ---------------------------------------------------------------------------
// conv0t: x = concat(d1[*,64], s1[*,32]), COUT=2. 32 lanes cooperate per row.
// ---------------------------------------------------------------------------
__global__ __launch_bounds__(256)
void sconv0t(const float* __restrict__ d1, const float* __restrict__ s1,
             const float* __restrict__ W /*[27,96,2]*/,
             const int* __restrict__ map, int N, float* __restrict__ out)
{
    const int tid  = threadIdx.x;
    const int lane = tid & 63;
    const int l32  = tid & 31;
    const int j    = blockIdx.x * 8 + (tid >> 5);

    int mk = (l32 < 27 && j < N) ? map[(size_t)l32 * N + j] : -1;

    float a0 = 0.f, a1 = 0.f;
    for (int k = 0; k < 27; ++k) {
        const int m = __shfl(mk, (lane & 32) + k);
        if (m < 0) continue;
        const float* w = W + (size_t)k * 96 * 2;
        const float x0 = d1[(size_t)m * 64 + l32];
        const float x1 = d1[(size_t)m * 64 + l32 + 32];
        const float x2 = s1[(size_t)m * 32 + l32];
        a0 = fmaf(x0, w[l32 * 2 + 0], a0);
        a1 = fmaf(x0, w[l32 * 2 + 1], a1);
        a0 = fmaf(x1, w[(l32 + 32) * 2 + 0], a0);
        a1 = fmaf(x1, w[(l32 + 32) * 2 + 1], a1);
        a0 = fmaf(x2, w[(l32 + 64) * 2 + 0], a0);
        a1 = fmaf(x2, w[(l32 + 64) * 2 + 1], a1);
    }
    #pragma unroll
    for (int off = 1; off < 32; off <<= 1) {
        a0 += __shfl_xor(a0, off, 32);
        a1 += __shfl_xor(a1, off, 32);
    }
    if (l32 == 0 && j < N) {
        out[(size_t)j * 2 + 0] = a0;
        out[(size_t)j * 2 + 1] = a1;
    }
}

// ---------------------------------------------------------------------------
// BN pass 1: per-channel sum and sum-of-squares -> atomicAdd into sums[2*C]
// Modest grid (256 blocks) -> ~33k total atomics, contention-free in practice.
// ---------------------------------------------------------------------------
template<int C>
__global__ __launch_bounds__(256)
void bn_reduce_kernel(const float* __restrict__ x, int N,
                      float* __restrict__ sums)
{
    constexpr int RG = 256 / C;
    const int tid = threadIdx.x;
    const int c   = tid % C;
    const int rg  = tid / C;
    float s = 0.f, s2 = 0.f;
    for (int j = blockIdx.x * RG + rg; j < N; j += gridDim.x * RG) {
        const float v = x[(size_t)j * C + c];
        s += v;
        s2 += v * v;
    }
    __shared__ float sh[2 * 256];
    sh[tid] = s;
    sh[256 + tid] = s2;
    __syncthreads();
    for (int stride = 128; stride >= C; stride >>= 1) {
        if (tid < stride) {
            sh[tid] += sh[tid + stride];
            sh[256 + tid] += sh[256 + tid + stride];
        }
        __syncthreads();
    }
    if (tid < C) {
        atomicAdd(&sums[c], sh[tid]);
        atomicAdd(&sums[C + c], sh[256 + tid]);
    }
}

// ---------------------------------------------------------------------------
// BN pass 2: x = relu((x - mu) * rsqrt(var + eps) * g + b), in place
// ---------------------------------------------------------------------------
template<int C>
__global__ __launch_bounds__(256)
void bn_apply_kernel(float* __restrict__ x, int N,
                     const float* __restrict__ sums,
                     const float* __restrict__ g, const float* __restrict__ b)
{
    const int tid = blockIdx.x * blockDim.x + threadIdx.x;
    const int c = tid % C;
    const float invN = 1.0f / (float)N;
    const float mean = sums[c] * invN;
    float var = sums[C + c] * invN - mean * mean;
    var = fmaxf(var, 0.f);
    const float sc = g[c] * rsqrtf(var + BN_EPS);
    const float sh = b[c] - mean * sc;
    const int rows_stride = (gridDim.x * blockDim.x) / C;
    for (int j = tid / C; j < N; j += rows_stride) {
        const size_t i = (size_t)j * C + c;
        const float v = fmaf(x[i], sc, sh);
        x[i] = v > 0.f ? v : 0.f;
    }
}

// ---------------------------------------------------------------------------
extern "C" void kernel_launch(void* const* d_in, const int* in_sizes, int n_in,
                              void* d_out, int out_size, void* d_ws, size_t ws_size,
                              hipStream_t stream)
{
    const float* feats = (const float*)d_in[0];
    const float* W0  = (const float*)d_in[1];
    const float* g0  = (const float*)d_in[2];
    const float* b0  = (const float*)d_in[3];
    const float* W1  = (const float*)d_in[4];
    const float* g1  = (const float*)d_in[5];
    const float* b1  = (const float*)d_in[6];
    const float* W2  = (const float*)d_in[7];
    const float* g2  = (const float*)d_in[8];
    const float* b2  = (const float*)d_in[9];
    const float* W2t = (const float*)d_in[10];
    const float* g2t = (const float*)d_in[11];
    const float* b2t = (const float*)d_in[12];
    const float* W1t = (const float*)d_in[13];
    const float* g1t = (const float*)d_in[14];
    const float* b1t = (const float*)d_in[15];
    const float* W0t = (const float*)d_in[16];
    const int* map0  = (const int*)d_in[17];
    const int* map1  = (const int*)d_in[18];
    const int* map2  = (const int*)d_in[19];
    const int* map2t = (const int*)d_in[20];
    const int* map1t = (const int*)d_in[21];
    const int* map0t = (const int*)d_in[22];

    const int N0 = in_sizes[0] / 16;
    const int N1 = in_sizes[18] / 27;
    const int N2 = in_sizes[19] / 27;

    float* ws = (float*)d_ws;
    float* y0 = ws;                      // [N0,32]  s1
    float* y1 = y0 + (size_t)N0 * 32;    // [N1,64]  s2
    float* y2 = y1 + (size_t)N1 * 64;    // [N2,128] s4
    float* y3 = y2 + (size_t)N2 * 128;   // [N1,64]  d2
    float* y4 = y3 + (size_t)N1 * 64;    // [N0,64]  d1
    float* sums  = y4 + (size_t)N0 * 64; // BN accumulators (704 floats)
    float* sums0 = sums;        // 2*32
    float* sums1 = sums + 64;   // 2*64
    float* sums2 = sums + 192;  // 2*128
    float* sums3 = sums + 448;  // 2*64
    float* sums4 = sums + 576;  // 2*64

    hipMemsetAsync(sums, 0, 704 * sizeof(float), stream);

    // block0: feats[N0,16] -> y0[N0,32]
    sconv0<<<(N0 + 7) / 8, 256, 0, stream>>>(feats, W0, map0, N0, y0);
    bn_reduce_kernel<32><<<256, 256, 0, stream>>>(y0, N0, sums0);
    bn_apply_kernel<32><<<512, 256, 0, stream>>>(y0, N0, sums0, g0, b0);

    // block1: s1[N0,32] -> y1[N1,64]   (R=8 -> 32 rows/block)
    sconv_big<32, 32, 64, 8><<<(N1 + 31) / 32, 256, 0, stream>>>(
        y0, nullptr, W1, map1, N1, y1);
    bn_reduce_kernel<64><<<256, 256, 0, stream>>>(y1, N1, sums1);
    bn_apply_kernel<64><<<512, 256, 0, stream>>>(y1, N1, sums1, g1, b1);

    // block2: s2[N1,64] -> y2[N2,128]  (R=4 -> 16 rows/block)
    sconv_big<64, 64, 128, 4><<<(N2 + 15) / 16, 256, 0, stream>>>(
        y1, nullptr, W2, map2, N2, y2);
    bn_reduce_kernel<128><<<256, 256, 0, stream>>>(y2, N2, sums2);
    bn_apply_kernel<128><<<512, 256, 0, stream>>>(y2, N2, sums2, g2, b2);

    // block2_tr: s4[N2,128] -> y3[N1,64]  (R=8 -> 32 rows/block)
    sconv_big<128, 128, 64, 8><<<(N1 + 31) / 32, 256, 0, stream>>>(
        y2, nullptr, W2t, map2t, N1, y3);
    bn_reduce_kernel<64><<<256, 256, 0, stream>>>(y3, N1, sums3);
    bn_apply_kernel<64><<<512, 256, 0, stream>>>(y3, N1, sums3, g2t, b2t);

    // block1_tr: concat(d2,s2)[N1,128] -> y4[N0,64]  (R=8)
    sconv_big<128, 64, 64, 8><<<(N0 + 31) / 32, 256, 0, stream>>>(
        y3, y1, W1t, map1t, N0, y4);
    bn_reduce_kernel<64><<<256, 256, 0, stream>>>(y4, N0, sums4);
    bn_apply_kernel<64><<<512, 256, 0, stream>>>(y4, N0, sums4, g1t, b1t);

    // block0_tr: concat(d1,s1)[N0,96] -> out[N0,2]
    sconv0t<<<(N0 + 7) / 8, 256, 0, stream>>>(y4, y0, W0t, map0t, N0,
                                              (float*)d_out);
}

// Round 5
// 1729.878 us; speedup vs baseline: 1.3171x; 1.1012x over previous
//
#include <hip/hip_runtime.h>
#include <cstddef>

#define BN_EPS 1e-5f

// ---------------------------------------------------------------------------
// Sparse conv for COUT in {64,128}. Block = 256 = 4 waves; each wave handles
// R consecutive output rows (lane = co, CPL = COUT/64 channels per lane).
// Map entries prefetched lane-parallel then broadcast (shfl+readfirstlane).
// KEY (round 5): invalid rows redirect their base pointer to a zeroed row
// (zrow) so the x loads are UNGUARDED -> compiler batches all tile loads in
// flight instead of sinking them into branches (round-4 disasm tell: 24 VGPRs
// = serial load->wait->FMA per row). FMAs stay guarded (wave-uniform scalar
// branch) to avoid paying ~3x redundant math at ~26% offset occupancy.
// ---------------------------------------------------------------------------
template<int CIN, int CINA, int COUT, int R>
__global__ __launch_bounds__(256, 4)
void sconv_big(const float* __restrict__ xA, const float* __restrict__ xB,
               const float* __restrict__ W, const int* __restrict__ map,
               int Nout, float* __restrict__ out, const float* __restrict__ zrow)
{
    constexpr int CINB = CIN - CINA;
    constexpr int CPL  = COUT / 64;
    constexpr int TI   = 8;
    const int lane = threadIdx.x & 63;
    const int wave = threadIdx.x >> 6;
    const int row0 = (blockIdx.x * 4 + wave) * R;

    int mk[R];
    #pragma unroll
    for (int r = 0; r < R; ++r) {
        const int j = row0 + r;
        mk[r] = (lane < 27 && j < Nout) ? map[(size_t)lane * Nout + j] : -1;
    }

    float acc[R][CPL];
    #pragma unroll
    for (int r = 0; r < R; ++r)
        #pragma unroll
        for (int c = 0; c < CPL; ++c) acc[r][c] = 0.f;

    for (int k = 0; k < 27; ++k) {
        int m[R];
        const float* pA[R];
        const float* pB[R];
        bool any = false;
        #pragma unroll
        for (int r = 0; r < R; ++r) {
            m[r] = __builtin_amdgcn_readfirstlane(__shfl(mk[r], k));
            const bool v = (m[r] >= 0);
            any |= v;
            pA[r] = v ? (xA + (size_t)m[r] * CINA) : zrow;   // uniform cselect
            if constexpr (CINB > 0)
                pB[r] = v ? (xB + (size_t)m[r] * CINB) : zrow;
        }
        if (!any) continue;

        const float* Wk = W + (size_t)k * CIN * COUT + lane;

        #pragma unroll
        for (int ci = 0; ci < CIN; ci += TI) {
            // ---- batched W tile loads (coalesced) ----
            float w[TI][CPL];
            #pragma unroll
            for (int u = 0; u < TI; ++u)
                #pragma unroll
                for (int c = 0; c < CPL; ++c)
                    w[u][c] = Wk[(size_t)(ci + u) * COUT + c * 64];

            // ---- UNGUARDED batched x loads (zrow makes invalid rows read 0) --
            float4 xv0[R], xv1[R];
            #pragma unroll
            for (int r = 0; r < R; ++r) {
                const float* xr;
                if constexpr (CINB > 0)
                    xr = (ci < CINA) ? (pA[r] + ci) : (pB[r] + (ci - CINA));
                else
                    xr = pA[r] + ci;
                xv0[r] = *(const float4*)xr;
                xv1[r] = *(const float4*)(xr + 4);
            }
            // keep all tile loads issued before any FMA consumes them
            __builtin_amdgcn_sched_barrier(0);

            // ---- guarded FMA blocks (wave-uniform scalar branches) ----
            #pragma unroll
            for (int r = 0; r < R; ++r) {
                if (m[r] < 0) continue;
                const float xx[TI] = {xv0[r].x, xv0[r].y, xv0[r].z, xv0[r].w,
                                      xv1[r].x, xv1[r].y, xv1[r].z, xv1[r].w};
                #pragma unroll
                for (int u = 0; u < TI; ++u)
                    #pragma unroll
                    for (int c = 0; c < CPL; ++c)
                        acc[r][c] = fmaf(xx[u], w[u][c], acc[r][c]);
            }
        }
    }

    #pragma unroll
    for (int r = 0; r < R; ++r) {
        const int j = row0 + r;
        if (j < Nout) {
            #pragma unroll
            for (int c = 0; c < CPL; ++c)
                out[(size_t)j * COUT + c * 64 + lane] = acc[r][c];
        }
    }
}

// ---------------------------------------------------------------------------
// conv0: CIN=16, COUT=32. One row per half-wave; block 256 = 8 rows.
// Whole-wave ballot skip (fires ~84% of k at stride-1 sparsity), then
// unguarded loads + unguarded FMAs via zrow (adds zeros for invalid halves).
// ---------------------------------------------------------------------------
__global__ __launch_bounds__(256)
void sconv0(const float* __restrict__ x, const float* __restrict__ W,
            const int* __restrict__ map, int N, float* __restrict__ out,
            const float* __restrict__ zrow)
{
    const int tid  = threadIdx.x;
    const int lane = tid & 63;
    const int l32  = tid & 31;
    const int co   = l32;
    const int j    = blockIdx.x * 8 + (tid >> 5);

    int mk = (l32 < 27 && j < N) ? map[(size_t)l32 * N + j] : -1;

    float a0 = 0.f, a1 = 0.f, a2 = 0.f, a3 = 0.f;
    for (int k = 0; k < 27; ++k) {
        const int m = __shfl(mk, (lane & 32) + k);
        if (__ballot(m >= 0) == 0ull) continue;
        const float* xr = (m >= 0) ? (x + (size_t)m * 16) : zrow;
        const float* wk = W + (size_t)k * 16 * 32 + co;
        const float4 xv0 = *(const float4*)xr;
        const float4 xv1 = *(const float4*)(xr + 4);
        const float4 xv2 = *(const float4*)(xr + 8);
        const float4 xv3 = *(const float4*)(xr + 12);
        a0 = fmaf(xv0.x, wk[0 * 32],  a0); a1 = fmaf(xv0.y, wk[1 * 32],  a1);
        a2 = fmaf(xv0.z, wk[2 * 32],  a2); a3 = fmaf(xv0.w, wk[3 * 32],  a3);
        a0 = fmaf(xv1.x, wk[4 * 32],  a0); a1 = fmaf(xv1.y, wk[5 * 32],  a1);
        a2 = fmaf(xv1.z, wk[6 * 32],  a2); a3 = fmaf(xv1.w, wk[7 * 32],  a3);
        a0 = fmaf(xv2.x, wk[8 * 32],  a0); a1 = fmaf(xv2.y, wk[9 * 32],  a1);
        a2 = fmaf(xv2.z, wk[10 * 32], a2); a3 = fmaf(xv2.w, wk[11 * 32], a3);
        a0 = fmaf(xv3.x, wk[12 * 32], a0); a1 = fmaf(xv3.y, wk[13 * 32], a1);
        a2 = fmaf(xv3.z, wk[14 * 32], a2); a3 = fmaf(xv3.w, wk[15 * 32], a3);
    }
    if (j < N) out[(size_t)j * 32 + co] = (a0 + a1) + (a2 + a3);
}

// ---------------------------------------------------------------------------
// conv0t: x = concat(d1[*,64], s1[*,32]), COUT=2. 32 lanes cooperate per row.
// Ballot skip + zrow-unguarded loads/FMAs; shfl-reduce tail.
// ---------------------------------------------------------------------------
__global__ __launch_bounds__(256)
void sconv0t(const float* __restrict__ d1, const float* __restrict__ s1,
             const float* __restrict__ W /*[27,96,2]*/,
             const int* __restrict__ map, int N, float* __restrict__ out,
             const float* __restrict__ zrow)
{
    const int tid  = threadIdx.x;
    const int lane = tid & 63;
    const int l32  = tid & 31;
    const int j    = blockIdx.x * 8 + (tid >> 5);

    int mk = (l32 < 27 && j < N) ? map[(size_t)l32 * N + j] : -1;

    float a0 = 0.f, a1 = 0.f;
    for (int k = 0; k < 27; ++k) {
        const int m = __shfl(mk, (lane & 32) + k);
        if (__ballot(m >= 0) == 0ull) continue;
        const float* p1 = (m >= 0) ? (d1 + (size_t)m * 64) : zrow;
        const float* p2 = (m >= 0) ? (s1 + (size_t)m * 32) : zrow;
        const float* w = W + (size_t)k * 96 * 2;
        const float x0 = p1[l32];
        const float x1 = p1[l32 + 32];
        const float x2 = p2[l32];
        a0 = fmaf(x0, w[l32 * 2 + 0], a0);
        a1 = fmaf(x0, w[l32 * 2 + 1], a1);
        a0 = fmaf(x1, w[(l32 + 32) * 2 + 0], a0);
        a1 = fmaf(x1, w[(l32 + 32) * 2 + 1], a1);
        a0 = fmaf(x2, w[(l32 + 64) * 2 + 0], a0);
        a1 = fmaf(x2, w[(l32 + 64) * 2 + 1], a1);
    }
    #pragma unroll
    for (int off = 1; off < 32; off <<= 1) {
        a0 += __shfl_xor(a0, off, 32);
        a1 += __shfl_xor(a1, off, 32);
    }
    if (l32 == 0 && j < N) {
        out[(size_t)j * 2 + 0] = a0;
        out[(size_t)j * 2 + 1] = a1;
    }
}

// ---------------------------------------------------------------------------
// BN pass 1: per-channel sum and sum-of-squares -> atomicAdd into sums[2*C]
// ---------------------------------------------------------------------------
template<int C>
__global__ __launch_bounds__(256)
void bn_reduce_kernel(const float* __restrict__ x, int N,
                      float* __restrict__ sums)
{
    constexpr int RG = 256 / C;
    const int tid = threadIdx.x;
    const int c   = tid % C;
    const int rg  = tid / C;
    float s = 0.f, s2 = 0.f;
    for (int j = blockIdx.x * RG + rg; j < N; j += gridDim.x * RG) {
        const float v = x[(size_t)j * C + c];
        s += v;
        s2 += v * v;
    }
    __shared__ float sh[2 * 256];
    sh[tid] = s;
    sh[256 + tid] = s2;
    __syncthreads();
    for (int stride = 128; stride >= C; stride >>= 1) {
        if (tid < stride) {
            sh[tid] += sh[tid + stride];
            sh[256 + tid] += sh[256 + tid + stride];
        }
        __syncthreads();
    }
    if (tid < C) {
        atomicAdd(&sums[c], sh[tid]);
        atomicAdd(&sums[C + c], sh[256 + tid]);
    }
}

// ---------------------------------------------------------------------------
// BN pass 2: x = relu((x - mu) * rsqrt(var + eps) * g + b), in place
// ---------------------------------------------------------------------------
template<int C>
__global__ __launch_bounds__(256)
void bn_apply_kernel(float* __restrict__ x, int N,
                     const float* __restrict__ sums,
                     const float* __restrict__ g, const float* __restrict__ b)
{
    const int tid = blockIdx.x * blockDim.x + threadIdx.x;
    const int c = tid % C;
    const float invN = 1.0f / (float)N;
    const float mean = sums[c] * invN;
    float var = sums[C + c] * invN - mean * mean;
    var = fmaxf(var, 0.f);
    const float sc = g[c] * rsqrtf(var + BN_EPS);
    const float sh = b[c] - mean * sc;
    const int rows_stride = (gridDim.x * blockDim.x) / C;
    for (int j = tid / C; j < N; j += rows_stride) {
        const size_t i = (size_t)j * C + c;
        const float v = fmaf(x[i], sc, sh);
        x[i] = v > 0.f ? v : 0.f;
    }
}

// ---------------------------------------------------------------------------
extern "C" void kernel_launch(void* const* d_in, const int* in_sizes, int n_in,
                              void* d_out, int out_size, void* d_ws, size_t ws_size,
                              hipStream_t stream)
{
    const float* feats = (const float*)d_in[0];
    const float* W0  = (const float*)d_in[1];
    const float* g0  = (const float*)d_in[2];
    const float* b0  = (const float*)d_in[3];
    const float* W1  = (const float*)d_in[4];
    const float* g1  = (const float*)d_in[5];
    const float* b1  = (const float*)d_in[6];
    const float* W2  = (const float*)d_in[7];
    const float* g2  = (const float*)d_in[8];
    const float* b2  = (const float*)d_in[9];
    const float* W2t = (const float*)d_in[10];
    const float* g2t = (const float*)d_in[11];
    const float* b2t = (const float*)d_in[12];
    const float* W1t = (const float*)d_in[13];
    const float* g1t = (const float*)d_in[14];
    const float* b1t = (const float*)d_in[15];
    const float* W0t = (const float*)d_in[16];
    const int* map0  = (const int*)d_in[17];
    const int* map1  = (const int*)d_in[18];
    const int* map2  = (const int*)d_in[19];
    const int* map2t = (const int*)d_in[20];
    const int* map1t = (const int*)d_in[21];
    const int* map0t = (const int*)d_in[22];

    const int N0 = in_sizes[0] / 16;
    const int N1 = in_sizes[18] / 27;
    const int N2 = in_sizes[19] / 27;

    float* ws = (float*)d_ws;
    float* y0 = ws;                      // [N0,32]  s1
    float* y1 = y0 + (size_t)N0 * 32;    // [N1,64]  s2
    float* y2 = y1 + (size_t)N1 * 64;    // [N2,128] s4
    float* y3 = y2 + (size_t)N2 * 128;   // [N1,64]  d2
    float* y4 = y3 + (size_t)N1 * 64;    // [N0,64]  d1
    float* sums  = y4 + (size_t)N0 * 64; // BN accumulators (704 floats)
    float* sums0 = sums;        // 2*32
    float* sums1 = sums + 64;   // 2*64
    float* sums2 = sums + 192;  // 2*128
    float* sums3 = sums + 448;  // 2*64
    float* sums4 = sums + 576;  // 2*64
    float* zrow  = sums + 704;  // 128 zeroed floats: dummy row for invalid m

    hipMemsetAsync(sums, 0, (704 + 128) * sizeof(float), stream);

    // block0: feats[N0,16] -> y0[N0,32]
    sconv0<<<(N0 + 7) / 8, 256, 0, stream>>>(feats, W0, map0, N0, y0, zrow);
    bn_reduce_kernel<32><<<256, 256, 0, stream>>>(y0, N0, sums0);
    bn_apply_kernel<32><<<512, 256, 0, stream>>>(y0, N0, sums0, g0, b0);

    // block1: s1[N0,32] -> y1[N1,64]   (R=8 -> 32 rows/block)
    sconv_big<32, 32, 64, 8><<<(N1 + 31) / 32, 256, 0, stream>>>(
        y0, nullptr, W1, map1, N1, y1, zrow);
    bn_reduce_kernel<64><<<256, 256, 0, stream>>>(y1, N1, sums1);
    bn_apply_kernel<64><<<512, 256, 0, stream>>>(y1, N1, sums1, g1, b1);

    // block2: s2[N1,64] -> y2[N2,128]  (R=4 -> 16 rows/block)
    sconv_big<64, 64, 128, 4><<<(N2 + 15) / 16, 256, 0, stream>>>(
        y1, nullptr, W2, map2, N2, y2, zrow);
    bn_reduce_kernel<128><<<256, 256, 0, stream>>>(y2, N2, sums2);
    bn_apply_kernel<128><<<512, 256, 0, stream>>>(y2, N2, sums2, g2, b2);

    // block2_tr: s4[N2,128] -> y3[N1,64]  (R=8 -> 32 rows/block)
    sconv_big<128, 128, 64, 8><<<(N1 + 31) / 32, 256, 0, stream>>>(
        y2, nullptr, W2t, map2t, N1, y3, zrow);
    bn_reduce_kernel<64><<<256, 256, 0, stream>>>(y3, N1, sums3);
    bn_apply_kernel<64><<<512, 256, 0, stream>>>(y3, N1, sums3, g2t, b2t);

    // block1_tr: concat(d2,s2)[N1,128] -> y4[N0,64]  (R=8)
    sconv_big<128, 64, 64, 8><<<(N0 + 31) / 32, 256, 0, stream>>>(
        y3, y1, W1t, map1t, N0, y4, zrow);
    bn_reduce_kernel<64><<<256, 256, 0, stream>>>(y4, N0, sums4);
    bn_apply_kernel<64><<<512, 256, 0, stream>>>(y4, N0, sums4, g1t, b1t);

    // block0_tr: concat(d1,s1)[N0,96] -> out[N0,2]
    sconv0t<<<(N0 + 7) / 8, 256, 0, stream>>>(y4, y0, W0t, map0t, N0,
                                              (float*)d_out, zrow);
}